// Round 6
// baseline (265.869 us; speedup 1.0000x reference)
//
#include <hip/hip_runtime.h>
#include <hip/hip_bf16.h>
#include <math.h>

typedef short bf16x8 __attribute__((ext_vector_type(8)));      // 8 bf16 = 4 VGPRs
typedef short short4v __attribute__((ext_vector_type(4)));     // 4 bf16 = 2 VGPRs
typedef float f32x4 __attribute__((ext_vector_type(4)));
typedef float float4v __attribute__((ext_vector_type(4)));
typedef unsigned short ushort4v __attribute__((ext_vector_type(4))); // 8 bytes

// cheap elu: exp(x)-1 via hardware v_exp_f32 (error ~1e-7 abs, threshold 3.4e-4)
static __device__ __forceinline__ float eluf(float x) {
  float e = __expf(x) - 1.0f;
  return x > 0.f ? x : e;
}
static __device__ __forceinline__ unsigned short f2bf(float f) {
  __hip_bfloat16 h = __float2bfloat16(f);
  return *reinterpret_cast<unsigned short*>(&h);
}
static __device__ __forceinline__ unsigned short f2bf_rne(float f) {
  union { float f; unsigned u; } v; v.f = f;
  unsigned r = v.u + 0x7FFFu + ((v.u >> 16) & 1u);
  return (unsigned short)(r >> 16);
}

// ---------------- prologue 1: h = elu(A_flat @ W1^T), h[256] ----------------
__global__ void k_hidden(const float* __restrict__ A, const float* __restrict__ W1,
                         float* __restrict__ hout) {
  int j = blockIdx.x, t = threadIdx.x;
  const float* row = W1 + (size_t)j * 4096;
  float s = 0.f;
  for (int i = t; i < 4096; i += 256) s += A[i] * row[i];
  __shared__ float red[256];
  red[t] = s; __syncthreads();
  for (int off = 128; off > 0; off >>= 1) {
    if (t < off) red[t] += red[t + off];
    __syncthreads();
  }
  if (t == 0) {
    float x = red[0];
    hout[j] = x > 0.f ? x : expm1f(x);   // prologue: keep precise
  }
}

// -------- prologue 2 (fused): blocks 0-63 = D rownorm; blocks 64+ = T-transpose
__global__ void k_pre2(const float* __restrict__ hbuf, const float* __restrict__ W2,
                       unsigned short* __restrict__ Dout,
                       const float* __restrict__ T1, const float* __restrict__ T2,
                       unsigned short* __restrict__ T1T, unsigned short* __restrict__ T2T) {
  int t = threadIdx.x;
  if (blockIdx.x < 64) {
    int x = blockIdx.x;
    int lane = t & 63, w = t >> 6;
    __shared__ float hs[256];
    __shared__ float ad[64];
    hs[t] = hbuf[t];
    __syncthreads();
    for (int ei = 0; ei < 16; ++ei) {
      int e = w * 16 + ei;
      const float* row = W2 + (size_t)(x * 64 + e) * 256;
      float p = 0.f;
      for (int q = 0; q < 4; ++q) p += row[q * 64 + lane] * hs[q * 64 + lane];
      for (int off = 32; off > 0; off >>= 1) p += __shfl_down(p, off);
      if (lane == 0) ad[e] = fmaxf(p, 0.f);
    }
    __syncthreads();
    if (t < 64) {
      float v = ad[t];
      float rs = v;
      for (int off = 1; off < 64; off <<= 1) rs += __shfl_xor(rs, off);
      Dout[x * 64 + t] = f2bf_rne(v / fmaxf(rs, 1e-6f));
    }
  } else {
    int idx = (blockIdx.x - 64) * 256 + t;      // 0 .. 163839
    const float* src = (idx < 81920) ? T1 : T2;
    unsigned short* dst = (idx < 81920) ? T1T : T2T;
    int o = (idx < 81920) ? idx : idx - 81920;
    int g = o >> 14;
    int r = o & 16383;
    int h = r >> 7;      // out row = n index
    int f = r & 127;     // out col = k index
    dst[o] = f2bf_rne(src[g * 16384 + f * 128 + h]);
  }
}

// ---------------- main: per (g,b): out = elu(D @ elu(mu@T1) @ T2) ----------
// Block = NB=4 consecutive b for one g; 4 waves; wave w owns n-block
// [32w,32w+32) of h (GEMM1/2 cols) and f (GEMM3 cols).
// GEMM1's C-frag IS the 16x16x16 B-frag layout -> h1 stays in registers.
// LDS = 2x16KB mu double-buffer; h2 aliases bcur. 2 barriers/iter.
// Register phases kept DISJOINT to avoid R5's spill: vn (prefetch) dies
// before t2b loads, which sit after B2 (can't hoist above barrier; LICM
// blocked by opaque vreg). Peak live ~144 < 168 cap of (256,3).
__launch_bounds__(256, 3)
__global__ void k_main(const float* __restrict__ mu,
                       const unsigned short* __restrict__ Dm,
                       const unsigned short* __restrict__ T1T,
                       const unsigned short* __restrict__ T2T,
                       float* __restrict__ out) {
  __shared__ __align__(16) char smem[32768];

  const int g = blockIdx.y, b0 = blockIdx.x * 4;
  const int t = threadIdx.x;
  const int lane = t & 63, w = t >> 6;
  const int l15 = lane & 15, lk = lane >> 4;
  const int nb = w * 32;

  // ---- hoist T1 and D fragments (loop-invariant) ----
  const unsigned short* t1g = T1T + g * 16384;
  bf16x8 tb0[4], tb1[4];
  #pragma unroll
  for (int kc = 0; kc < 4; ++kc) {
    int k0 = kc * 32 + lk * 8;
    tb0[kc] = *(const bf16x8*)(const void*)(t1g + (nb + l15) * 128 + k0);
    tb1[kc] = *(const bf16x8*)(const void*)(t1g + (nb + 16 + l15) * 128 + k0);
  }
  // A-frags for GEMM2 (16x16x16): D[x=mp*16+l15][e = kc*16 + lk*4 + j]
  short4v aDf[4][4];
  #pragma unroll
  for (int mp = 0; mp < 4; ++mp)
    #pragma unroll
    for (int kc = 0; kc < 4; ++kc)
      aDf[mp][kc] = *(const short4v*)(const void*)(Dm + (mp * 16 + l15) * 64 + kc * 16 + lk * 4);

  // ---- prologue: stage mu for it=0 into buf0 ----
  {
    const float4v* src = (const float4v*)(mu + (size_t)(g * 1024 + b0) * 8192);
    #pragma unroll
    for (int k = 0; k < 8; ++k) {
      int q = t + k * 256;
      float4v v = src[q];
      int row = q >> 5, col4 = (q & 31) * 4;
      ushort4v u;
      u[0] = f2bf(v[0]); u[1] = f2bf(v[1]); u[2] = f2bf(v[2]); u[3] = f2bf(v[3]);
      *(ushort4v*)(smem + ((row * 256 + col4 * 2) ^ ((row & 7) << 4))) = u;
    }
  }
  __syncthreads();

  #pragma unroll 1
  for (int it = 0; it < 4; ++it) {
    char* bcur = smem + ((it & 1) << 14);
    char* bnxt = smem + (((it + 1) & 1) << 14);
    const bool pre = (it < 3);

    // issue next-iter mu loads; pin here so hipcc can't sink them
    float4v vn[8];
    if (pre) {
      const float4v* srcn = (const float4v*)(mu + (size_t)(g * 1024 + b0 + it + 1) * 8192);
      #pragma unroll
      for (int k = 0; k < 8; ++k) vn[k] = srcn[t + k * 256];
      __builtin_amdgcn_sched_barrier(0);
    }

    // ---- GEMM1: h1 = mu @ T1 (M=e 64, N=h 128, K=f 128), acc in regs ----
    f32x4 acc[4][2];
    #pragma unroll
    for (int m = 0; m < 4; ++m) { acc[m][0] = (f32x4){0,0,0,0}; acc[m][1] = (f32x4){0,0,0,0}; }
    #pragma unroll
    for (int kc = 0; kc < 4; ++kc) {
      int k0 = kc * 32 + lk * 8;
      #pragma unroll
      for (int m = 0; m < 4; ++m) {
        int row = m * 16 + l15;
        bf16x8 a = *(const bf16x8*)(bcur + ((row * 256 + k0 * 2) ^ ((row & 7) << 4)));
        acc[m][0] = __builtin_amdgcn_mfma_f32_16x16x32_bf16(a, tb0[kc], acc[m][0], 0, 0, 0);
        acc[m][1] = __builtin_amdgcn_mfma_f32_16x16x32_bf16(a, tb1[kc], acc[m][1], 0, 0, 0);
      }
    }

    // ---- elu + cvt: acc[m][n] -> bf16x4 B-frags for GEMM2 (pure registers) --
    short4v bfr[4][2];
    #pragma unroll
    for (int m = 0; m < 4; ++m)
      #pragma unroll
      for (int n = 0; n < 2; ++n) {
        short4v s;
        s[0] = (short)f2bf(eluf(acc[m][n][0]));
        s[1] = (short)f2bf(eluf(acc[m][n][1]));
        s[2] = (short)f2bf(eluf(acc[m][n][2]));
        s[3] = (short)f2bf(eluf(acc[m][n][3]));
        bfr[m][n] = s;
      }

    // ---- GEMM2: h2 = D @ h1 (M=x 64, N=h 128, K=e 64) via 16x16x16 ----
    f32x4 acc2[4][2];
    #pragma unroll
    for (int mp = 0; mp < 4; ++mp) { acc2[mp][0] = (f32x4){0,0,0,0}; acc2[mp][1] = (f32x4){0,0,0,0}; }
    #pragma unroll
    for (int kc = 0; kc < 4; ++kc)
      #pragma unroll
      for (int mp = 0; mp < 4; ++mp) {
        acc2[mp][0] = __builtin_amdgcn_mfma_f32_16x16x16bf16_1k(aDf[mp][kc], bfr[kc][0], acc2[mp][0], 0, 0, 0);
        acc2[mp][1] = __builtin_amdgcn_mfma_f32_16x16x16bf16_1k(aDf[mp][kc], bfr[kc][1], acc2[mp][1], 0, 0, 0);
      }

    __syncthreads();   // B1: all waves' GEMM1 mu reads done -> bcur reusable

    // h2[x][h] scatter into bcur (b16 writes, swizzled on x)
    #pragma unroll
    for (int mp = 0; mp < 4; ++mp)
      #pragma unroll
      for (int n = 0; n < 2; ++n) {
        int hc = nb + n * 16 + l15;
        #pragma unroll
        for (int r = 0; r < 4; ++r) {
          int x = mp * 16 + lk * 4 + r;
          *(unsigned short*)(bcur + ((x * 256 + hc * 2) ^ ((x & 7) << 4))) = f2bf(acc2[mp][n][r]);
        }
      }
    // stage mu_{it+1} -> bnxt (vn waitcnt lands here, covered by GEMM1+GEMM2)
    if (pre) {
      #pragma unroll
      for (int k = 0; k < 8; ++k) {
        int q = t + k * 256;
        int row = q >> 5, col4 = (q & 31) * 4;
        ushort4v u;
        u[0] = f2bf(vn[k][0]); u[1] = f2bf(vn[k][1]);
        u[2] = f2bf(vn[k][2]); u[3] = f2bf(vn[k][3]);
        *(ushort4v*)(bnxt + ((row * 256 + col4 * 2) ^ ((row & 7) << 4))) = u;
      }
    }
    __syncthreads();   // B2: h2 + mu_next visible

    // ---- T2 frags: loaded AFTER B2 so they never overlap vn/acc2 (reg peak);
    //      opaque vreg blocks LICM; loads can't hoist above the barrier. L2-hot.
    int t2off = g * 16384;
    asm volatile("" : "+v"(t2off));
    const unsigned short* t2g = T2T + t2off;
    bf16x8 t2b0[4], t2b1[4];
    #pragma unroll
    for (int kc = 0; kc < 4; ++kc) {
      int k0 = kc * 32 + lk * 8;
      t2b0[kc] = *(const bf16x8*)(const void*)(t2g + (nb + l15) * 128 + k0);
      t2b1[kc] = *(const bf16x8*)(const void*)(t2g + (nb + 16 + l15) * 128 + k0);
    }

    // ---- GEMM3: out = elu(h2 @ T2) (M=x 64, N=f 128, K=h 128) ----
    f32x4 acc3[4][2];
    #pragma unroll
    for (int m = 0; m < 4; ++m) { acc3[m][0] = (f32x4){0,0,0,0}; acc3[m][1] = (f32x4){0,0,0,0}; }
    #pragma unroll
    for (int kc = 0; kc < 4; ++kc) {
      int k0 = kc * 32 + lk * 8;
      #pragma unroll
      for (int m = 0; m < 4; ++m) {
        int row = m * 16 + l15;
        bf16x8 a = *(const bf16x8*)(bcur + ((row * 256 + k0 * 2) ^ ((row & 7) << 4)));
        acc3[m][0] = __builtin_amdgcn_mfma_f32_16x16x32_bf16(a, t2b0[kc], acc3[m][0], 0, 0, 0);
        acc3[m][1] = __builtin_amdgcn_mfma_f32_16x16x32_bf16(a, t2b1[kc], acc3[m][1], 0, 0, 0);
      }
    }
    float* ob = out + (size_t)(g * 1024 + b0 + it) * 8192;
    #pragma unroll
    for (int m = 0; m < 4; ++m)
      #pragma unroll
      for (int n = 0; n < 2; ++n) {
        int f = nb + n * 16 + l15;
        #pragma unroll
        for (int r = 0; r < 4; ++r) {
          int e = m * 16 + lk * 4 + r;
          ob[e * 128 + f] = eluf(acc3[m][n][r]);
        }
      }
  }
}

extern "C" void kernel_launch(void* const* d_in, const int* in_sizes, int n_in,
                              void* d_out, int out_size, void* d_ws, size_t ws_size,
                              hipStream_t stream) {
  const float* mu = (const float*)d_in[0];
  const float* A  = (const float*)d_in[1];
  const float* W1 = (const float*)d_in[2];
  const float* W2 = (const float*)d_in[3];
  const float* T1 = (const float*)d_in[4];
  const float* T2 = (const float*)d_in[5];
  float* out = (float*)d_out;

  char* ws = (char*)d_ws;
  float* hbuf          = (float*)ws;                     // 1 KB
  unsigned short* Dm   = (unsigned short*)(ws + 1024);   // 8 KB
  unsigned short* T1T  = (unsigned short*)(ws + 9216);   // 160 KB
  unsigned short* T2T  = (unsigned short*)(ws + 173056); // 160 KB

  hipLaunchKernelGGL(k_hidden, dim3(256), dim3(256), 0, stream, A, W1, hbuf);
  hipLaunchKernelGGL(k_pre2,   dim3(704), dim3(256), 0, stream, hbuf, W2, Dm, T1, T2, T1T, T2T);
  hipLaunchKernelGGL(k_main,   dim3(256, 5), dim3(256), 0, stream, mu, Dm, T1T, T2T, out);
}

// Round 7
// 172.457 us; speedup vs baseline: 1.5416x; 1.5416x over previous
//
#include <hip/hip_runtime.h>
#include <hip/hip_bf16.h>
#include <math.h>

typedef short bf16x8 __attribute__((ext_vector_type(8)));      // 8 bf16 = 4 VGPRs
typedef short short4v __attribute__((ext_vector_type(4)));     // 4 bf16 = 2 VGPRs
typedef float f32x4 __attribute__((ext_vector_type(4)));
typedef float float4v __attribute__((ext_vector_type(4)));
typedef unsigned short ushort4v __attribute__((ext_vector_type(4))); // 8 bytes

// cheap elu: exp(x)-1 via hardware v_exp_f32 (error ~1e-7 abs, threshold 3.4e-4)
static __device__ __forceinline__ float eluf(float x) {
  float e = __expf(x) - 1.0f;
  return x > 0.f ? x : e;
}
static __device__ __forceinline__ unsigned short f2bf(float f) {
  __hip_bfloat16 h = __float2bfloat16(f);
  return *reinterpret_cast<unsigned short*>(&h);
}
static __device__ __forceinline__ unsigned short f2bf_rne(float f) {
  union { float f; unsigned u; } v; v.f = f;
  unsigned r = v.u + 0x7FFFu + ((v.u >> 16) & 1u);
  return (unsigned short)(r >> 16);
}
// 8 consecutive f32 -> bf16x8 fragment
static __device__ __forceinline__ bf16x8 cvt8(float4v lo, float4v hi) {
  bf16x8 r;
  r[0] = (short)f2bf(lo[0]); r[1] = (short)f2bf(lo[1]);
  r[2] = (short)f2bf(lo[2]); r[3] = (short)f2bf(lo[3]);
  r[4] = (short)f2bf(hi[0]); r[5] = (short)f2bf(hi[1]);
  r[6] = (short)f2bf(hi[2]); r[7] = (short)f2bf(hi[3]);
  return r;
}

// ---------------- prologue 1: h = elu(A_flat @ W1^T), h[256] ----------------
__global__ void k_hidden(const float* __restrict__ A, const float* __restrict__ W1,
                         float* __restrict__ hout) {
  int j = blockIdx.x, t = threadIdx.x;
  const float* row = W1 + (size_t)j * 4096;
  float s = 0.f;
  for (int i = t; i < 4096; i += 256) s += A[i] * row[i];
  __shared__ float red[256];
  red[t] = s; __syncthreads();
  for (int off = 128; off > 0; off >>= 1) {
    if (t < off) red[t] += red[t + off];
    __syncthreads();
  }
  if (t == 0) {
    float x = red[0];
    hout[j] = x > 0.f ? x : expm1f(x);   // prologue: keep precise
  }
}

// -------- prologue 2 (fused): blocks 0-63 = D rownorm; blocks 64+ = T-transpose
__global__ void k_pre2(const float* __restrict__ hbuf, const float* __restrict__ W2,
                       unsigned short* __restrict__ Dout,
                       const float* __restrict__ T1, const float* __restrict__ T2,
                       unsigned short* __restrict__ T1T, unsigned short* __restrict__ T2T) {
  int t = threadIdx.x;
  if (blockIdx.x < 64) {
    int x = blockIdx.x;
    int lane = t & 63, w = t >> 6;
    __shared__ float hs[256];
    __shared__ float ad[64];
    hs[t] = hbuf[t];
    __syncthreads();
    for (int ei = 0; ei < 16; ++ei) {
      int e = w * 16 + ei;
      const float* row = W2 + (size_t)(x * 64 + e) * 256;
      float p = 0.f;
      for (int q = 0; q < 4; ++q) p += row[q * 64 + lane] * hs[q * 64 + lane];
      for (int off = 32; off > 0; off >>= 1) p += __shfl_down(p, off);
      if (lane == 0) ad[e] = fmaxf(p, 0.f);
    }
    __syncthreads();
    if (t < 64) {
      float v = ad[t];
      float rs = v;
      for (int off = 1; off < 64; off <<= 1) rs += __shfl_xor(rs, off);
      Dout[x * 64 + t] = f2bf_rne(v / fmaxf(rs, 1e-6f));
    }
  } else {
    int idx = (blockIdx.x - 64) * 256 + t;      // 0 .. 163839
    const float* src = (idx < 81920) ? T1 : T2;
    unsigned short* dst = (idx < 81920) ? T1T : T2T;
    int o = (idx < 81920) ? idx : idx - 81920;
    int g = o >> 14;
    int r = o & 16383;
    int h = r >> 7;      // out row = n index
    int f = r & 127;     // out col = k index
    dst[o] = f2bf_rne(src[g * 16384 + f * 128 + h]);
  }
}

// ---------------- main: per (g,b): out = elu(D @ elu(mu@T1) @ T2) ----------
// LEAN structure: one (g,b) tile per block; 4 waves; wave w owns n-cols
// [32w,32w+32). NO mu LDS staging — GEMM1 A-frags read DIRECTLY from global
// (each elem consumed once; 4-wave redundancy dedups in L1/L2). GEMM1->GEMM2
// handoff in registers (16x16x16 B-frag identity). Only h2 goes through LDS
// (16 KB, XOR-swizzled) -> ONE barrier per block. All T/D frag loads are
// single-use (no loop) so pressure is transient; (256,2) avoids the 84/84
// unified-RF split spill seen with (256,3). Out stores nontemporal to keep
// L3 for mu.
__launch_bounds__(256, 2)
__global__ void k_main(const float* __restrict__ mu,
                       const unsigned short* __restrict__ Dm,
                       const unsigned short* __restrict__ T1T,
                       const unsigned short* __restrict__ T2T,
                       float* __restrict__ out) {
  __shared__ __align__(16) char s_h2[16384];   // [64 x][128 h] bf16, swz

  const int g = blockIdx.y, b = blockIdx.x;
  const int t = threadIdx.x;
  const int lane = t & 63, w = t >> 6;
  const int l15 = lane & 15, lk = lane >> 4;
  const int nb = w * 32;

  const float* mub = mu + (size_t)(g * 1024 + b) * 8192;
  const unsigned short* t1g = T1T + g * 16384;

  // ---- GEMM1: h1 = mu @ T1 (M=e 64, N=h 128, K=f 128); A direct from global
  f32x4 acc[4][2];
  #pragma unroll
  for (int m = 0; m < 4; ++m) { acc[m][0] = (f32x4){0,0,0,0}; acc[m][1] = (f32x4){0,0,0,0}; }
  #pragma unroll
  for (int kc = 0; kc < 4; ++kc) {
    int k0 = kc * 32 + lk * 8;
    bf16x8 b0 = *(const bf16x8*)(const void*)(t1g + (nb + l15) * 128 + k0);
    bf16x8 b1 = *(const bf16x8*)(const void*)(t1g + (nb + 16 + l15) * 128 + k0);
    #pragma unroll
    for (int m = 0; m < 4; ++m) {
      const float4v* ap = (const float4v*)(mub + (m * 16 + l15) * 128 + k0);
      bf16x8 a = cvt8(ap[0], ap[1]);
      acc[m][0] = __builtin_amdgcn_mfma_f32_16x16x32_bf16(a, b0, acc[m][0], 0, 0, 0);
      acc[m][1] = __builtin_amdgcn_mfma_f32_16x16x32_bf16(a, b1, acc[m][1], 0, 0, 0);
    }
  }

  // ---- elu + cvt: acc -> bf16x4 B-frags for GEMM2 (pure registers) ----
  short4v bfr[4][2];
  #pragma unroll
  for (int m = 0; m < 4; ++m)
    #pragma unroll
    for (int n = 0; n < 2; ++n) {
      short4v s;
      s[0] = (short)f2bf(eluf(acc[m][n][0]));
      s[1] = (short)f2bf(eluf(acc[m][n][1]));
      s[2] = (short)f2bf(eluf(acc[m][n][2]));
      s[3] = (short)f2bf(eluf(acc[m][n][3]));
      bfr[m][n] = s;
    }

  // ---- GEMM2: h2 = D @ h1 (M=x 64, N=h 128, K=e 64) via 16x16x16 ----
  f32x4 acc2[4][2];
  #pragma unroll
  for (int mp = 0; mp < 4; ++mp) { acc2[mp][0] = (f32x4){0,0,0,0}; acc2[mp][1] = (f32x4){0,0,0,0}; }
  #pragma unroll
  for (int kc = 0; kc < 4; ++kc) {
    #pragma unroll
    for (int mp = 0; mp < 4; ++mp) {
      short4v aD = *(const short4v*)(const void*)(Dm + (mp * 16 + l15) * 64 + kc * 16 + lk * 4);
      acc2[mp][0] = __builtin_amdgcn_mfma_f32_16x16x16bf16_1k(aD, bfr[kc][0], acc2[mp][0], 0, 0, 0);
      acc2[mp][1] = __builtin_amdgcn_mfma_f32_16x16x16bf16_1k(aD, bfr[kc][1], acc2[mp][1], 0, 0, 0);
    }
  }

  // ---- h2[x][h] scatter into LDS (b16 writes, swizzled on x) ----
  #pragma unroll
  for (int mp = 0; mp < 4; ++mp)
    #pragma unroll
    for (int n = 0; n < 2; ++n) {
      int hc = nb + n * 16 + l15;
      #pragma unroll
      for (int r = 0; r < 4; ++r) {
        int x = mp * 16 + lk * 4 + r;
        *(unsigned short*)(s_h2 + ((x * 256 + hc * 2) ^ ((x & 7) << 4))) = f2bf(acc2[mp][n][r]);
      }
    }
  __syncthreads();   // the ONLY barrier: h2 visible to all waves

  // ---- GEMM3: out = elu(h2 @ T2) (M=x 64, N=f 128, K=h 128) ----
  const unsigned short* t2g = T2T + g * 16384;
  f32x4 acc3[4][2];
  #pragma unroll
  for (int m = 0; m < 4; ++m) { acc3[m][0] = (f32x4){0,0,0,0}; acc3[m][1] = (f32x4){0,0,0,0}; }
  #pragma unroll
  for (int kc = 0; kc < 4; ++kc) {
    int k0 = kc * 32 + lk * 8;
    bf16x8 c0 = *(const bf16x8*)(const void*)(t2g + (nb + l15) * 128 + k0);
    bf16x8 c1 = *(const bf16x8*)(const void*)(t2g + (nb + 16 + l15) * 128 + k0);
    #pragma unroll
    for (int m = 0; m < 4; ++m) {
      int row = m * 16 + l15;
      bf16x8 a = *(const bf16x8*)(s_h2 + ((row * 256 + k0 * 2) ^ ((row & 7) << 4)));
      acc3[m][0] = __builtin_amdgcn_mfma_f32_16x16x32_bf16(a, c0, acc3[m][0], 0, 0, 0);
      acc3[m][1] = __builtin_amdgcn_mfma_f32_16x16x32_bf16(a, c1, acc3[m][1], 0, 0, 0);
    }
  }
  float* ob = out + (size_t)(g * 1024 + b) * 8192;
  #pragma unroll
  for (int m = 0; m < 4; ++m)
    #pragma unroll
    for (int n = 0; n < 2; ++n) {
      int f = nb + n * 16 + l15;
      #pragma unroll
      for (int r = 0; r < 4; ++r) {
        int e = m * 16 + lk * 4 + r;
        __builtin_nontemporal_store(eluf(acc3[m][n][r]), ob + e * 128 + f);
      }
    }
}

extern "C" void kernel_launch(void* const* d_in, const int* in_sizes, int n_in,
                              void* d_out, int out_size, void* d_ws, size_t ws_size,
                              hipStream_t stream) {
  const float* mu = (const float*)d_in[0];
  const float* A  = (const float*)d_in[1];
  const float* W1 = (const float*)d_in[2];
  const float* W2 = (const float*)d_in[3];
  const float* T1 = (const float*)d_in[4];
  const float* T2 = (const float*)d_in[5];
  float* out = (float*)d_out;

  char* ws = (char*)d_ws;
  float* hbuf          = (float*)ws;                     // 1 KB
  unsigned short* Dm   = (unsigned short*)(ws + 1024);   // 8 KB
  unsigned short* T1T  = (unsigned short*)(ws + 9216);   // 160 KB
  unsigned short* T2T  = (unsigned short*)(ws + 173056); // 160 KB

  hipLaunchKernelGGL(k_hidden, dim3(256), dim3(256), 0, stream, A, W1, hbuf);
  hipLaunchKernelGGL(k_pre2,   dim3(704), dim3(256), 0, stream, hbuf, W2, Dm, T1, T2, T1T, T2T);
  hipLaunchKernelGGL(k_main,   dim3(1024, 5), dim3(256), 0, stream, mu, Dm, T1T, T2T, out);
}

// Round 8
// 136.319 us; speedup vs baseline: 1.9503x; 1.2651x over previous
//
#include <hip/hip_runtime.h>
#include <hip/hip_bf16.h>
#include <math.h>

typedef short bf16x8 __attribute__((ext_vector_type(8)));      // 8 bf16 = 4 VGPRs
typedef short short4v __attribute__((ext_vector_type(4)));     // 4 bf16 = 2 VGPRs
typedef float f32x4 __attribute__((ext_vector_type(4)));
typedef float float4v __attribute__((ext_vector_type(4)));
typedef unsigned short ushort4v __attribute__((ext_vector_type(4))); // 8 bytes

// cheap elu: exp(x)-1 via hardware v_exp_f32 (error ~1e-7 abs, threshold 3.4e-4)
static __device__ __forceinline__ float eluf(float x) {
  float e = __expf(x) - 1.0f;
  return x > 0.f ? x : e;
}
static __device__ __forceinline__ unsigned short f2bf(float f) {
  __hip_bfloat16 h = __float2bfloat16(f);
  return *reinterpret_cast<unsigned short*>(&h);
}
static __device__ __forceinline__ unsigned short f2bf_rne(float f) {
  union { float f; unsigned u; } v; v.f = f;
  unsigned r = v.u + 0x7FFFu + ((v.u >> 16) & 1u);
  return (unsigned short)(r >> 16);
}
// 8 consecutive f32 -> bf16x8 fragment
static __device__ __forceinline__ bf16x8 cvt8(float4v lo, float4v hi) {
  bf16x8 r;
  r[0] = (short)f2bf(lo[0]); r[1] = (short)f2bf(lo[1]);
  r[2] = (short)f2bf(lo[2]); r[3] = (short)f2bf(lo[3]);
  r[4] = (short)f2bf(hi[0]); r[5] = (short)f2bf(hi[1]);
  r[6] = (short)f2bf(hi[2]); r[7] = (short)f2bf(hi[3]);
  return r;
}
// async global->LDS, 16B per lane (dest must be wave-uniform base + lane*16)
static __device__ __forceinline__ void load_lds16(const void* g, void* l) {
  __builtin_amdgcn_global_load_lds(
      (const __attribute__((address_space(1))) unsigned int*)g,
      (__attribute__((address_space(3))) unsigned int*)l, 16, 0, 0);
}

// ---------------- prologue 1: h = elu(A_flat @ W1^T), h[256] ----------------
__global__ void k_hidden(const float* __restrict__ A, const float* __restrict__ W1,
                         float* __restrict__ hout) {
  int j = blockIdx.x, t = threadIdx.x;
  const float* row = W1 + (size_t)j * 4096;
  float s = 0.f;
  for (int i = t; i < 4096; i += 256) s += A[i] * row[i];
  __shared__ float red[256];
  red[t] = s; __syncthreads();
  for (int off = 128; off > 0; off >>= 1) {
    if (t < off) red[t] += red[t + off];
    __syncthreads();
  }
  if (t == 0) {
    float x = red[0];
    hout[j] = x > 0.f ? x : expm1f(x);   // prologue: keep precise
  }
}

// -------- prologue 2 (fused): blocks 0-63 = D rownorm; blocks 64+ = T-transpose
__global__ void k_pre2(const float* __restrict__ hbuf, const float* __restrict__ W2,
                       unsigned short* __restrict__ Dout,
                       const float* __restrict__ T1, const float* __restrict__ T2,
                       unsigned short* __restrict__ T1T, unsigned short* __restrict__ T2T) {
  int t = threadIdx.x;
  if (blockIdx.x < 64) {
    int x = blockIdx.x;
    int lane = t & 63, w = t >> 6;
    __shared__ float hs[256];
    __shared__ float ad[64];
    hs[t] = hbuf[t];
    __syncthreads();
    for (int ei = 0; ei < 16; ++ei) {
      int e = w * 16 + ei;
      const float* row = W2 + (size_t)(x * 64 + e) * 256;
      float p = 0.f;
      for (int q = 0; q < 4; ++q) p += row[q * 64 + lane] * hs[q * 64 + lane];
      for (int off = 32; off > 0; off >>= 1) p += __shfl_down(p, off);
      if (lane == 0) ad[e] = fmaxf(p, 0.f);
    }
    __syncthreads();
    if (t < 64) {
      float v = ad[t];
      float rs = v;
      for (int off = 1; off < 64; off <<= 1) rs += __shfl_xor(rs, off);
      Dout[x * 64 + t] = f2bf_rne(v / fmaxf(rs, 1e-6f));
    }
  } else {
    int idx = (blockIdx.x - 64) * 256 + t;      // 0 .. 163839
    const float* src = (idx < 81920) ? T1 : T2;
    unsigned short* dst = (idx < 81920) ? T1T : T2T;
    int o = (idx < 81920) ? idx : idx - 81920;
    int g = o >> 14;
    int r = o & 16383;
    int h = r >> 7;      // out row = n index
    int f = r & 127;     // out col = k index
    dst[o] = f2bf_rne(src[g * 16384 + f * 128 + h]);
  }
}

// ---------------- main: per (g,b): out = elu(D @ elu(mu@T1) @ T2) ----------
// One (g,b) tile per block; 4 waves; wave w owns n-cols [32w,32w+32).
// mu staged as f32 into LDS via ASYNC global_load_lds (width 16): zero VGPR
// round-trip, zero VALU on staging, one vmcnt drain at the barrier. Swizzle
// applied on the GLOBAL SOURCE address (linear LDS dest + inverse-swz src +
// swz on read): src = d ^ ((row&7)<<4); A-frag reads use the same XOR ->
// rows 0-7 tile all 32 banks (2 lanes/bank = free). f32->bf16 cvt happens at
// fragment-read time. GEMM1->GEMM2 handoff in registers (16x16x16 B-frag
// identity). h2 (bf16, 16KB, XOR-swz) aliases mu[0:16K] after B1.
// LDS 32KB -> 5 blocks/CU. T1/T2/D frags per-use from L1/L2 (tiny, hot).
__launch_bounds__(256, 2)
__global__ void k_main(const float* __restrict__ mu,
                       const unsigned short* __restrict__ Dm,
                       const unsigned short* __restrict__ T1T,
                       const unsigned short* __restrict__ T2T,
                       float* __restrict__ out) {
  __shared__ __align__(16) char smem[32768];   // mu f32 [64][128] swz-src; [0:16K] reused as h2
  char* s_h2 = smem;

  const int g = blockIdx.y, b = blockIdx.x;
  const int t = threadIdx.x;
  const int lane = t & 63, w = t >> 6;
  const int l15 = lane & 15, lk = lane >> 4;
  const int nb = w * 32;

  const char* gtile = (const char*)(mu + (size_t)(g * 1024 + b) * 8192);
  const unsigned short* t1g = T1T + g * 16384;

  // ---- async stage mu (f32, 32KB): 8 x global_load_lds, swizzled source ----
  #pragma unroll
  for (int k = 0; k < 8; ++k) {
    int d = k * 4096 + t * 16;              // linear LDS byte; per-wave base + lane*16
    int row = d >> 9;                        // 512B rows
    int src = d ^ ((row & 7) << 4);
    load_lds16(gtile + src, smem + d);
  }
  __syncthreads();   // B0: drains the 8 async loads; mu visible

  // ---- GEMM1: h1 = mu @ T1 (M=e 64, N=h 128, K=f 128); A from LDS f32 ----
  f32x4 acc[4][2];
  #pragma unroll
  for (int m = 0; m < 4; ++m) { acc[m][0] = (f32x4){0,0,0,0}; acc[m][1] = (f32x4){0,0,0,0}; }
  #pragma unroll
  for (int kc = 0; kc < 4; ++kc) {
    int k0 = kc * 32 + lk * 8;
    bf16x8 b0 = *(const bf16x8*)(const void*)(t1g + (nb + l15) * 128 + k0);
    bf16x8 b1 = *(const bf16x8*)(const void*)(t1g + (nb + 16 + l15) * 128 + k0);
    #pragma unroll
    for (int m = 0; m < 4; ++m) {
      int row = m * 16 + l15;
      int rbyte = row * 512 + k0 * 4;
      int sw = (row & 7) << 4;
      float4v lo = *(const float4v*)(smem + (rbyte ^ sw));
      float4v hi = *(const float4v*)(smem + ((rbyte + 16) ^ sw));
      bf16x8 a = cvt8(lo, hi);
      acc[m][0] = __builtin_amdgcn_mfma_f32_16x16x32_bf16(a, b0, acc[m][0], 0, 0, 0);
      acc[m][1] = __builtin_amdgcn_mfma_f32_16x16x32_bf16(a, b1, acc[m][1], 0, 0, 0);
    }
  }

  // ---- elu + cvt: acc -> bf16x4 B-frags for GEMM2 (pure registers) ----
  short4v bfr[4][2];
  #pragma unroll
  for (int m = 0; m < 4; ++m)
    #pragma unroll
    for (int n = 0; n < 2; ++n) {
      short4v s;
      s[0] = (short)f2bf(eluf(acc[m][n][0]));
      s[1] = (short)f2bf(eluf(acc[m][n][1]));
      s[2] = (short)f2bf(eluf(acc[m][n][2]));
      s[3] = (short)f2bf(eluf(acc[m][n][3]));
      bfr[m][n] = s;
    }

  // ---- GEMM2: h2 = D @ h1 (M=x 64, N=h 128, K=e 64) via 16x16x16 ----
  f32x4 acc2[4][2];
  #pragma unroll
  for (int mp = 0; mp < 4; ++mp) { acc2[mp][0] = (f32x4){0,0,0,0}; acc2[mp][1] = (f32x4){0,0,0,0}; }
  #pragma unroll
  for (int kc = 0; kc < 4; ++kc) {
    #pragma unroll
    for (int mp = 0; mp < 4; ++mp) {
      short4v aD = *(const short4v*)(const void*)(Dm + (mp * 16 + l15) * 64 + kc * 16 + lk * 4);
      acc2[mp][0] = __builtin_amdgcn_mfma_f32_16x16x16bf16_1k(aD, bfr[kc][0], acc2[mp][0], 0, 0, 0);
      acc2[mp][1] = __builtin_amdgcn_mfma_f32_16x16x16bf16_1k(aD, bfr[kc][1], acc2[mp][1], 0, 0, 0);
    }
  }

  __syncthreads();   // B1: all waves done reading mu -> [0:16K] reusable for h2

  // ---- h2[x][h] scatter into LDS (b16 writes, bf16 swizzle on x) ----
  #pragma unroll
  for (int mp = 0; mp < 4; ++mp)
    #pragma unroll
    for (int n = 0; n < 2; ++n) {
      int hc = nb + n * 16 + l15;
      #pragma unroll
      for (int r = 0; r < 4; ++r) {
        int x = mp * 16 + lk * 4 + r;
        *(unsigned short*)(s_h2 + ((x * 256 + hc * 2) ^ ((x & 7) << 4))) = f2bf(acc2[mp][n][r]);
      }
    }
  __syncthreads();   // B2: h2 visible

  // ---- GEMM3: out = elu(h2 @ T2) (M=x 64, N=f 128, K=h 128) ----
  const unsigned short* t2g = T2T + g * 16384;
  f32x4 acc3[4][2];
  #pragma unroll
  for (int m = 0; m < 4; ++m) { acc3[m][0] = (f32x4){0,0,0,0}; acc3[m][1] = (f32x4){0,0,0,0}; }
  #pragma unroll
  for (int kc = 0; kc < 4; ++kc) {
    int k0 = kc * 32 + lk * 8;
    bf16x8 c0 = *(const bf16x8*)(const void*)(t2g + (nb + l15) * 128 + k0);
    bf16x8 c1 = *(const bf16x8*)(const void*)(t2g + (nb + 16 + l15) * 128 + k0);
    #pragma unroll
    for (int m = 0; m < 4; ++m) {
      int row = m * 16 + l15;
      bf16x8 a = *(const bf16x8*)(s_h2 + ((row * 256 + k0 * 2) ^ ((row & 7) << 4)));
      acc3[m][0] = __builtin_amdgcn_mfma_f32_16x16x32_bf16(a, c0, acc3[m][0], 0, 0, 0);
      acc3[m][1] = __builtin_amdgcn_mfma_f32_16x16x32_bf16(a, c1, acc3[m][1], 0, 0, 0);
    }
  }
  float* ob = out + (size_t)(g * 1024 + b) * 8192;
  #pragma unroll
  for (int m = 0; m < 4; ++m)
    #pragma unroll
    for (int n = 0; n < 2; ++n) {
      int f = nb + n * 16 + l15;
      #pragma unroll
      for (int r = 0; r < 4; ++r) {
        int e = m * 16 + lk * 4 + r;
        ob[e * 128 + f] = eluf(acc3[m][n][r]);
      }
    }
}

extern "C" void kernel_launch(void* const* d_in, const int* in_sizes, int n_in,
                              void* d_out, int out_size, void* d_ws, size_t ws_size,
                              hipStream_t stream) {
  const float* mu = (const float*)d_in[0];
  const float* A  = (const float*)d_in[1];
  const float* W1 = (const float*)d_in[2];
  const float* W2 = (const float*)d_in[3];
  const float* T1 = (const float*)d_in[4];
  const float* T2 = (const float*)d_in[5];
  float* out = (float*)d_out;

  char* ws = (char*)d_ws;
  float* hbuf          = (float*)ws;                     // 1 KB
  unsigned short* Dm   = (unsigned short*)(ws + 1024);   // 8 KB
  unsigned short* T1T  = (unsigned short*)(ws + 9216);   // 160 KB
  unsigned short* T2T  = (unsigned short*)(ws + 173056); // 160 KB

  hipLaunchKernelGGL(k_hidden, dim3(256), dim3(256), 0, stream, A, W1, hbuf);
  hipLaunchKernelGGL(k_pre2,   dim3(704), dim3(256), 0, stream, hbuf, W2, Dm, T1, T2, T1T, T2T);
  hipLaunchKernelGGL(k_main,   dim3(1024, 5), dim3(256), 0, stream, mu, Dm, T1T, T2T, out);
}